// Round 2
// baseline (175.900 us; speedup 1.0000x reference)
//
#include <hip/hip_runtime.h>
#include <math.h>

// SoftCodebook fused kernel v4 for MI355X (gfx950).
// p = softmax( (h/||h||) @ (proto/||proto||)^T / 0.1 ),  z = p @ proto
// v4 = v3 (no LDS staging, no barriers, pre-swizzled B fragments in L2) plus:
//   - amdgpu_waves_per_eu(4,4): grid caps occupancy at 4 waves/SIMD anyway, so
//     let the allocator use the full 128-VGPR tier instead of folding to 64
//     (v3's VGPR=64 serialized the 144 global loads per wave -> latency-bound).
//   - hand software-pipeline: 3-slot rotating B-fragment buffers, prefetch
//     distance 2 (8 loads in flight during MFMA issue) in both GEMMs.
//   - z-B group 0/1 loads issued BEFORE softmax (independent), scale loads
//     hoisted before sim GEMM; log2e folded into softmax slope (exp2 path).

#define EPS 1e-12f
#define TAU_INV 10.0f

typedef _Float16 f16x8 __attribute__((ext_vector_type(8)));
typedef float f32x4 __attribute__((ext_vector_type(4)));

#define PB_STRIDE 136   // halves per pbuf row: 272 B (16B-aligned rows, <=2-way bank)

// ---------------------------------------------------------------------------
// k_prep: per-prototype L2 norm -> scale[128].  grid 128 x 64.
__global__ void k_prep(const float* __restrict__ proto, float* __restrict__ scale) {
    const int kp = blockIdx.x;
    const int lane = threadIdx.x;
    const float4 v = ((const float4*)(proto + kp * 256))[lane];
    float s = v.x * v.x + v.y * v.y + v.z * v.z + v.w * v.w;
    #pragma unroll
    for (int msk = 1; msk < 64; msk <<= 1) s += __shfl_xor(s, msk, 64);
    if (lane == 0) scale[kp] = fmaxf(sqrtf(s), EPS);
}

// ---------------------------------------------------------------------------
// k_frag: build per-lane B-fragment images (f16 cbar) in ws.  grid 128 x 64.
//   simB[(t*8+c)*64 + lane][j] = cbar[t*16+m][c*32+q*8+j]   (sim B operand)
//   zB [(dt*4+kc)*64 + lane][j] = cbar[kc*32+q*8+j][dt*16+m] (z  B operand)
// where m = lane&15, q = lane>>4 (matches mfma_f32_16x16x32_f16 B layout).
__global__ void k_frag(const float* __restrict__ proto,
                       const float* __restrict__ scale,
                       _Float16* __restrict__ simB, _Float16* __restrict__ zB) {
    const int b = blockIdx.x;
    const int lane = threadIdx.x;
    const int m = lane & 15, q = lane >> 4;
    _Float16 r[8];
    if (b < 64) {
        const int t = b >> 3, c = b & 7;
        const int kp = t * 16 + m;
        const float inv = 1.0f / scale[kp];
        const float* src = proto + (size_t)kp * 256 + c * 32 + q * 8;
        #pragma unroll
        for (int j = 0; j < 8; j++) r[j] = (_Float16)(src[j] * inv);
        *(f16x8*)(simB + ((size_t)b * 64 + lane) * 8) = *(const f16x8*)r;
    } else {
        const int b2 = b - 64;
        const int dt = b2 >> 2, kc = b2 & 3;
        #pragma unroll
        for (int j = 0; j < 8; j++) {
            const int kk = kc * 32 + q * 8 + j;
            r[j] = (_Float16)(proto[(size_t)kk * 256 + dt * 16 + m] / scale[kk]);
        }
        *(f16x8*)(zB + ((size_t)b2 * 64 + lane) * 8) = *(const f16x8*)r;
    }
}

// ---------------------------------------------------------------------------
// k_main: 256 threads = 4 independent waves, 16 rows/wave, grid = M/64 = 1024.
// No __syncthreads: pbuf is wave-private (rows w*16..w*16+15), B comes from L2.
__global__ __launch_bounds__(256)
__attribute__((amdgpu_waves_per_eu(4, 4)))
void k_main(
    const float* __restrict__ h,
    const float* __restrict__ scale,
    const _Float16* __restrict__ simB,
    const _Float16* __restrict__ zB,
    float* __restrict__ out_p,
    float* __restrict__ out_z) {

    __shared__ _Float16 pbuf[64 * PB_STRIDE];   // 17408 B

    const int tid = threadIdx.x;
    const int w = tid >> 6;
    const int lane = tid & 63;
    const int m = lane & 15;
    const int quad = lane >> 4;
    const int row0 = blockIdx.x * 64 + w * 16;

    // --- load this wave's 16 h-rows (lane quarter-rows), sumsq + raw f16 convert
    const float* hrow = h + (size_t)(row0 + m) * 256 + quad * 8;
    f16x8 A[8];
    float s = 0.f;
    #pragma unroll
    for (int c = 0; c < 8; c++) {
        const float4 a = *(const float4*)(hrow + c * 32);
        const float4 b = *(const float4*)(hrow + c * 32 + 4);
        s += a.x * a.x + a.y * a.y + a.z * a.z + a.w * a.w;
        s += b.x * b.x + b.y * b.y + b.z * b.z + b.w * b.w;
        A[c][0] = (_Float16)a.x; A[c][1] = (_Float16)a.y;
        A[c][2] = (_Float16)a.z; A[c][3] = (_Float16)a.w;
        A[c][4] = (_Float16)b.x; A[c][5] = (_Float16)b.y;
        A[c][6] = (_Float16)b.z; A[c][7] = (_Float16)b.w;
    }

    // prototype scales for the z-path A operand (issued early, used in softmax)
    float sc_l[8];
    #pragma unroll
    for (int t = 0; t < 8; t++) sc_l[t] = scale[t * 16 + m];

    s += __shfl_xor(s, 16, 64);
    s += __shfl_xor(s, 32, 64);
    const float inv = 1.0f / fmaxf(sqrtf(s), EPS);   // 1/||h[row m]||

    // softmax slope per output row r (rows quad*4+r; inv lives in lane quad*4+r).
    // log2e folded in: p = exp2((sim - mx) * tinv)
    float tinv[4];
    #pragma unroll
    for (int r = 0; r < 4; r++)
        tinv[r] = TAU_INV * 1.44269504f * __shfl(inv, quad * 4 + r, 64);

    // --- sim GEMM on RAW h: acc[t][row r] = h[row]·cbar[t*16+m]
    // 64 fragments in 16 groups of 4; 3-slot rotation, prefetch distance 2.
    const f16x8* sB = (const f16x8*)simB;
    f32x4 acc[8] = {};
    f16x8 Bb[3][4];
    #pragma unroll
    for (int i = 0; i < 4; i++) Bb[0][i] = sB[(0 * 4 + i) * 64 + lane];
    #pragma unroll
    for (int i = 0; i < 4; i++) Bb[1][i] = sB[(1 * 4 + i) * 64 + lane];
    #pragma unroll
    for (int g = 0; g < 16; g++) {
        if (g < 14) {
            #pragma unroll
            for (int i = 0; i < 4; i++)
                Bb[(g + 2) % 3][i] = sB[((g + 2) * 4 + i) * 64 + lane];
        }
        const int t = g >> 1;
        #pragma unroll
        for (int i = 0; i < 4; i++)
            acc[t] = __builtin_amdgcn_mfma_f32_16x16x32_f16(
                A[(g & 1) * 4 + i], Bb[g % 3][i], acc[t], 0, 0, 0);
    }

    // --- prefetch first two z-B groups (independent of softmax)
    const f16x8* zB8 = (const f16x8*)zB;
    f16x8 Zb[3][4];
    #pragma unroll
    for (int i = 0; i < 4; i++) Zb[0][i] = zB8[(0 * 4 + i) * 64 + lane];
    #pragma unroll
    for (int i = 0; i < 4; i++) Zb[1][i] = zB8[(1 * 4 + i) * 64 + lane];

    // --- softmax over K=128 per row; norm folded into slope tinv[r]
    #pragma unroll
    for (int r = 0; r < 4; r++) {
        float mx = acc[0][r];
        #pragma unroll
        for (int t = 1; t < 8; t++) mx = fmaxf(mx, acc[t][r]);
        #pragma unroll
        for (int msk = 1; msk < 16; msk <<= 1) mx = fmaxf(mx, __shfl_xor(mx, msk, 64));
        float e[8];
        float sum = 0.f;
        #pragma unroll
        for (int t = 0; t < 8; t++) {
            e[t] = __builtin_amdgcn_exp2f((acc[t][r] - mx) * tinv[r]);
            sum += e[t];
        }
        #pragma unroll
        for (int msk = 1; msk < 16; msk <<= 1) sum += __shfl_xor(sum, msk, 64);
        const float rs = 1.0f / sum;
        const int grow = row0 + quad * 4 + r;
        float* po = out_p + (size_t)grow * 128;
        const int prow = w * 16 + quad * 4 + r;
        #pragma unroll
        for (int t = 0; t < 8; t++) {
            const float p = e[t] * rs;
            po[t * 16 + m] = p;
            pbuf[prow * PB_STRIDE + t * 16 + m] = (_Float16)(p * sc_l[t]);
        }
    }

    // --- z GEMM: A = (p*scale) fragments from wave-private pbuf (lgkmcnt-ordered,
    // no block barrier), B from L2 with 3-slot rotation, prefetch distance 2.
    f16x8 Ap[4];
    #pragma unroll
    for (int kc = 0; kc < 4; kc++)
        Ap[kc] = *(const f16x8*)&pbuf[(w * 16 + m) * PB_STRIDE + kc * 32 + quad * 8];

    #pragma unroll
    for (int dt = 0; dt < 16; dt++) {
        if (dt < 14) {
            #pragma unroll
            for (int i = 0; i < 4; i++)
                Zb[(dt + 2) % 3][i] = zB8[((dt + 2) * 4 + i) * 64 + lane];
        }
        f32x4 zc = {};
        #pragma unroll
        for (int kc = 0; kc < 4; kc++)
            zc = __builtin_amdgcn_mfma_f32_16x16x32_f16(
                Ap[kc], Zb[dt % 3][kc], zc, 0, 0, 0);
        #pragma unroll
        for (int r = 0; r < 4; r++)
            out_z[(size_t)(row0 + quad * 4 + r) * 256 + dt * 16 + m] = zc[r];
    }
}

// ---------------------------------------------------------------------------
extern "C" void kernel_launch(void* const* d_in, const int* in_sizes, int n_in,
                              void* d_out, int out_size, void* d_ws, size_t ws_size,
                              hipStream_t stream) {
    const float* h_in  = (const float*)d_in[0];   // (B,P,D) fp32, B*P=65536, D=256
    const float* proto = (const float*)d_in[1];   // (K,D) fp32, K=128

    const int M = in_sizes[0] / 256;              // 65536 rows

    // ws: scale[128] f32 (1 KiB slot) | simB (64 KiB) | zB (64 KiB)
    float*     scale = (float*)d_ws;
    _Float16*  simB  = (_Float16*)((char*)d_ws + 1024);
    _Float16*  zB    = (_Float16*)((char*)d_ws + 1024 + 65536);

    float* out_p = (float*)d_out;                 // (M,128)
    float* out_z = out_p + (size_t)M * 128;       // (M,256)

    k_prep<<<dim3(128), dim3(64), 0, stream>>>(proto, scale);
    k_frag<<<dim3(128), dim3(64), 0, stream>>>(proto, scale, simB, zB);
    k_main<<<dim3(M / 64), dim3(256), 0, stream>>>(h_in, scale, simB, zB,
                                                   out_p, out_z);
}

// Round 3
// 171.449 us; speedup vs baseline: 1.0260x; 1.0260x over previous
//
#include <hip/hip_runtime.h>
#include <math.h>

// SoftCodebook fused kernel v5 for MI355X (gfx950).
// p = softmax( (h/||h||) @ (proto/||proto||)^T / 0.1 ),  z = p @ proto
// v5 = v4 structure, but the software pipeline is made UNSINKABLE:
//   - PIN(x) = empty asm volatile "+v" on each fragment after the NEXT group's
//     loads are issued. The asm redefines the value, so (a) its load cannot be
//     sunk to the use site by the pressure-aware scheduler (which is what
//     silently serialized v3/v4 -> VGPR_Count=64, ~1 load in flight, 96K-cycle
//     waves), and (b) the compiler emits a counted s_waitcnt vmcnt(N) at the
//     pin -> ~8 loads in flight steady-state. Loads remain ordinary IR loads,
//     so all waitcnt bookkeeping stays compiler-managed (no asm-ds hazards).
//   - amdgpu_waves_per_eu(3): VGPR budget 168 so pins force prefetch, not spill.
//   - h loaded as one 16-load burst into a flat array, then reduced/converted.

#define EPS 1e-12f
#define TAU_INV 10.0f

typedef _Float16 f16x8 __attribute__((ext_vector_type(8)));
typedef float f32x4 __attribute__((ext_vector_type(4)));

#define PB_STRIDE 136   // halves per pbuf row: 272 B (16B-aligned rows, <=2-way bank)

#define PIN(x) asm volatile("" : "+v"(x))

// ---------------------------------------------------------------------------
// k_prep: per-prototype L2 norm -> scale[128].  grid 128 x 64.
__global__ void k_prep(const float* __restrict__ proto, float* __restrict__ scale) {
    const int kp = blockIdx.x;
    const int lane = threadIdx.x;
    const float4 v = ((const float4*)(proto + kp * 256))[lane];
    float s = v.x * v.x + v.y * v.y + v.z * v.z + v.w * v.w;
    #pragma unroll
    for (int msk = 1; msk < 64; msk <<= 1) s += __shfl_xor(s, msk, 64);
    if (lane == 0) scale[kp] = fmaxf(sqrtf(s), EPS);
}

// ---------------------------------------------------------------------------
// k_frag: build per-lane B-fragment images (f16 cbar) in ws.  grid 128 x 64.
//   simB[(t*8+c)*64 + lane][j] = cbar[t*16+m][c*32+q*8+j]   (sim B operand)
//   zB [(dt*4+kc)*64 + lane][j] = cbar[kc*32+q*8+j][dt*16+m] (z  B operand)
// where m = lane&15, q = lane>>4 (matches mfma_f32_16x16x32_f16 B layout).
__global__ void k_frag(const float* __restrict__ proto,
                       const float* __restrict__ scale,
                       _Float16* __restrict__ simB, _Float16* __restrict__ zB) {
    const int b = blockIdx.x;
    const int lane = threadIdx.x;
    const int m = lane & 15, q = lane >> 4;
    _Float16 r[8];
    if (b < 64) {
        const int t = b >> 3, c = b & 7;
        const int kp = t * 16 + m;
        const float inv = 1.0f / scale[kp];
        const float* src = proto + (size_t)kp * 256 + c * 32 + q * 8;
        #pragma unroll
        for (int j = 0; j < 8; j++) r[j] = (_Float16)(src[j] * inv);
        *(f16x8*)(simB + ((size_t)b * 64 + lane) * 8) = *(const f16x8*)r;
    } else {
        const int b2 = b - 64;
        const int dt = b2 >> 2, kc = b2 & 3;
        #pragma unroll
        for (int j = 0; j < 8; j++) {
            const int kk = kc * 32 + q * 8 + j;
            r[j] = (_Float16)(proto[(size_t)kk * 256 + dt * 16 + m] / scale[kk]);
        }
        *(f16x8*)(zB + ((size_t)b2 * 64 + lane) * 8) = *(const f16x8*)r;
    }
}

// ---------------------------------------------------------------------------
// k_main: 256 threads = 4 independent waves, 16 rows/wave, grid = M/64 = 1024.
// No __syncthreads: pbuf is wave-private (rows w*16..w*16+15), B comes from L2.
__global__ __launch_bounds__(256)
__attribute__((amdgpu_waves_per_eu(3)))
void k_main(
    const float* __restrict__ h,
    const float* __restrict__ scale,
    const _Float16* __restrict__ simB,
    const _Float16* __restrict__ zB,
    float* __restrict__ out_p,
    float* __restrict__ out_z) {

    __shared__ _Float16 pbuf[64 * PB_STRIDE];   // 17408 B

    const int tid = threadIdx.x;
    const int w = tid >> 6;
    const int lane = tid & 63;
    const int m = lane & 15;
    const int quad = lane >> 4;
    const int row0 = blockIdx.x * 64 + w * 16;

    // --- h burst: 16 float4 loads issued together, then sumsq + f16 convert
    const float* hrow = h + (size_t)(row0 + m) * 256 + quad * 8;
    float4 hv[16];
    #pragma unroll
    for (int c = 0; c < 8; c++) {
        hv[c * 2 + 0] = *(const float4*)(hrow + c * 32);
        hv[c * 2 + 1] = *(const float4*)(hrow + c * 32 + 4);
    }
    float s = 0.f;
    #pragma unroll
    for (int i = 0; i < 16; i++) {
        s += hv[i].x * hv[i].x + hv[i].y * hv[i].y
           + hv[i].z * hv[i].z + hv[i].w * hv[i].w;
    }
    f16x8 A[8];
    #pragma unroll
    for (int c = 0; c < 8; c++) {
        A[c][0] = (_Float16)hv[c*2+0].x; A[c][1] = (_Float16)hv[c*2+0].y;
        A[c][2] = (_Float16)hv[c*2+0].z; A[c][3] = (_Float16)hv[c*2+0].w;
        A[c][4] = (_Float16)hv[c*2+1].x; A[c][5] = (_Float16)hv[c*2+1].y;
        A[c][6] = (_Float16)hv[c*2+1].z; A[c][7] = (_Float16)hv[c*2+1].w;
    }
    s += __shfl_xor(s, 16, 64);
    s += __shfl_xor(s, 32, 64);
    const float inv = 1.0f / fmaxf(sqrtf(s), EPS);   // 1/||h[row m]||

    // softmax slope per output row r (rows quad*4+r; inv lives in lane quad*4+r).
    // log2e folded in: p = exp2((sim - mx) * tinv)
    float tinv[4];
    #pragma unroll
    for (int r = 0; r < 4; r++)
        tinv[r] = TAU_INV * 1.44269504f * __shfl(inv, quad * 4 + r, 64);

    // --- sim GEMM on RAW h: acc[t][row r] = h[row]·cbar[t*16+m]
    // 64 fragments in 16 groups of 4; 3-slot rotation, prefetch distance 2,
    // PIN forces group residency only after the +2 group's loads are issued.
    const f16x8* sB = (const f16x8*)simB;
    f32x4 acc[8] = {};
    f16x8 Bb[3][4];
    #pragma unroll
    for (int i = 0; i < 4; i++) Bb[0][i] = sB[(0 * 4 + i) * 64 + lane];
    #pragma unroll
    for (int i = 0; i < 4; i++) Bb[1][i] = sB[(1 * 4 + i) * 64 + lane];
    #pragma unroll
    for (int g = 0; g < 16; g++) {
        if (g < 14) {
            #pragma unroll
            for (int i = 0; i < 4; i++)
                Bb[(g + 2) % 3][i] = sB[((g + 2) * 4 + i) * 64 + lane];
        }
        PIN(Bb[g % 3][0]); PIN(Bb[g % 3][1]);
        PIN(Bb[g % 3][2]); PIN(Bb[g % 3][3]);
        const int t = g >> 1;
        #pragma unroll
        for (int i = 0; i < 4; i++)
            acc[t] = __builtin_amdgcn_mfma_f32_16x16x32_f16(
                A[(g & 1) * 4 + i], Bb[g % 3][i], acc[t], 0, 0, 0);
    }

    // prototype scales for the z-path A operand (L2 hits; overlap with softmax)
    float sc_l[8];
    #pragma unroll
    for (int t = 0; t < 8; t++) sc_l[t] = scale[t * 16 + m];

    // --- softmax over K=128 per row; norm folded into slope tinv[r]
    #pragma unroll
    for (int r = 0; r < 4; r++) {
        float mx = acc[0][r];
        #pragma unroll
        for (int t = 1; t < 8; t++) mx = fmaxf(mx, acc[t][r]);
        #pragma unroll
        for (int msk = 1; msk < 16; msk <<= 1) mx = fmaxf(mx, __shfl_xor(mx, msk, 64));
        float e[8];
        float sum = 0.f;
        #pragma unroll
        for (int t = 0; t < 8; t++) {
            e[t] = __builtin_amdgcn_exp2f((acc[t][r] - mx) * tinv[r]);
            sum += e[t];
        }
        #pragma unroll
        for (int msk = 1; msk < 16; msk <<= 1) sum += __shfl_xor(sum, msk, 64);
        const float rs = 1.0f / sum;
        const int grow = row0 + quad * 4 + r;
        float* po = out_p + (size_t)grow * 128;
        const int prow = w * 16 + quad * 4 + r;
        #pragma unroll
        for (int t = 0; t < 8; t++) {
            const float p = e[t] * rs;
            po[t * 16 + m] = p;
            pbuf[prow * PB_STRIDE + t * 16 + m] = (_Float16)(p * sc_l[t]);
        }
    }

    // --- z GEMM: A = (p*scale) fragments from wave-private pbuf (lgkmcnt-ordered,
    // no block barrier), B from L2, 3-slot rotation + PIN, distance 2.
    const f16x8* zB8 = (const f16x8*)zB;
    f16x8 Zb[3][4];
    #pragma unroll
    for (int i = 0; i < 4; i++) Zb[0][i] = zB8[(0 * 4 + i) * 64 + lane];
    #pragma unroll
    for (int i = 0; i < 4; i++) Zb[1][i] = zB8[(1 * 4 + i) * 64 + lane];

    f16x8 Ap[4];
    #pragma unroll
    for (int kc = 0; kc < 4; kc++)
        Ap[kc] = *(const f16x8*)&pbuf[(w * 16 + m) * PB_STRIDE + kc * 32 + quad * 8];

    #pragma unroll
    for (int dt = 0; dt < 16; dt++) {
        if (dt < 14) {
            #pragma unroll
            for (int i = 0; i < 4; i++)
                Zb[(dt + 2) % 3][i] = zB8[((dt + 2) * 4 + i) * 64 + lane];
        }
        PIN(Zb[dt % 3][0]); PIN(Zb[dt % 3][1]);
        PIN(Zb[dt % 3][2]); PIN(Zb[dt % 3][3]);
        f32x4 zc = {};
        #pragma unroll
        for (int kc = 0; kc < 4; kc++)
            zc = __builtin_amdgcn_mfma_f32_16x16x32_f16(
                Ap[kc], Zb[dt % 3][kc], zc, 0, 0, 0);
        #pragma unroll
        for (int r = 0; r < 4; r++)
            out_z[(size_t)(row0 + quad * 4 + r) * 256 + dt * 16 + m] = zc[r];
    }
}

// ---------------------------------------------------------------------------
extern "C" void kernel_launch(void* const* d_in, const int* in_sizes, int n_in,
                              void* d_out, int out_size, void* d_ws, size_t ws_size,
                              hipStream_t stream) {
    const float* h_in  = (const float*)d_in[0];   // (B,P,D) fp32, B*P=65536, D=256
    const float* proto = (const float*)d_in[1];   // (K,D) fp32, K=128

    const int M = in_sizes[0] / 256;              // 65536 rows

    // ws: scale[128] f32 (1 KiB slot) | simB (64 KiB) | zB (64 KiB)
    float*     scale = (float*)d_ws;
    _Float16*  simB  = (_Float16*)((char*)d_ws + 1024);
    _Float16*  zB    = (_Float16*)((char*)d_ws + 1024 + 65536);

    float* out_p = (float*)d_out;                 // (M,128)
    float* out_z = out_p + (size_t)M * 128;       // (M,256)

    k_prep<<<dim3(128), dim3(64), 0, stream>>>(proto, scale);
    k_frag<<<dim3(128), dim3(64), 0, stream>>>(proto, scale, simB, zB);
    k_main<<<dim3(M / 64), dim3(256), 0, stream>>>(h_in, scale, simB, zB,
                                                   out_p, out_z);
}